// Round 15
// baseline (459.617 us; speedup 1.0000x reference)
//
#include <hip/hip_runtime.h>

// GraphGenRnn — R14: node chain fused again (R11 structure) but with CHUNKED
// sync: flags every 16 steps (20 signals total) instead of every step (320).
// R11's regression was per-signal cross-XCD cost (~1.5us) x 320; R13 showed
// store-drain wasn't node_l0's cost, and total = node_chain + longest_edge.
// Blocks 0-3 L0, 4-7 xgemm, 8-11 L1; in-chunk steps use lgkm-only barriers.
// Edge kernel unchanged (R10: f16 reg weights + DPP + fdot2).

typedef __attribute__((ext_vector_type(8))) short short8;
typedef __attribute__((ext_vector_type(4))) short short4v;
typedef __attribute__((ext_vector_type(4))) float floatx4;
typedef _Float16 half2v __attribute__((ext_vector_type(2)));

#define NG 64
#define NMAX 161
#define CH 16
#define NCH 10

__device__ __forceinline__ float sgm(float x) {
  return __builtin_amdgcn_rcpf(1.0f + __expf(-x));
}
__device__ __forceinline__ float tanhf_(float x) {
  return 2.0f * __builtin_amdgcn_rcpf(1.0f + __expf(-2.0f * x)) - 1.0f;
}
__device__ __forceinline__ unsigned short f2b(float x) {
  union { float f; unsigned u; } v; v.f = x;
  unsigned r = v.u + 0x7fffu + ((v.u >> 16) & 1u);   // RNE to bf16
  return (unsigned short)(r >> 16);
}
__device__ __forceinline__ float b2f(unsigned short h) {
  union { unsigned u; float f; } v; v.u = ((unsigned)h) << 16; return v.f;
}
__device__ __forceinline__ half2v pkh(float a, float b) {
  return __builtin_bit_cast(half2v, __builtin_amdgcn_cvt_pkrtz(a, b));
}
// barrier that orders LDS only (no vmcnt drain of in-flight global stores)
__device__ __forceinline__ void barrier_lds() {
  asm volatile("s_waitcnt lgkmcnt(0)" ::: "memory");
  __builtin_amdgcn_s_barrier();
}

// DPP row_ror:N within 16-lane rows: out[i] = in[(i+N)&15]
#define RORF(x, N) __builtin_bit_cast(float, __builtin_amdgcn_update_dpp(      \
    __builtin_bit_cast(int, (x)), __builtin_bit_cast(int, (x)),                \
    0x120 | (N), 0xF, 0xF, false))

__device__ __forceinline__ void rotpack(float h, half2v* out) {
  const float r1  = RORF(h, 1),  r2  = RORF(h, 2),  r3  = RORF(h, 3);
  const float r4  = RORF(h, 4),  r5  = RORF(h, 5),  r6  = RORF(h, 6);
  const float r7  = RORF(h, 7),  r8  = RORF(h, 8),  r9  = RORF(h, 9);
  const float r10 = RORF(h, 10), r11 = RORF(h, 11), r12 = RORF(h, 12);
  const float r13 = RORF(h, 13), r14 = RORF(h, 14), r15 = RORF(h, 15);
  out[0] = pkh(h,   r1);
  out[1] = pkh(r2,  r3);
  out[2] = pkh(r4,  r5);
  out[3] = pkh(r6,  r7);
  out[4] = pkh(r8,  r9);
  out[5] = pkh(r10, r11);
  out[6] = pkh(r12, r13);
  out[7] = pkh(r14, r15);
}

// ---------------------------------------------------------------------------
// node_fused: 12 blocks x 512 threads, chunk-pipelined (CH=16).
// ---------------------------------------------------------------------------
__global__ __launch_bounds__(512) void node_fused(
    const float* __restrict__ gene,   // [64][128]
    const float* __restrict__ entw,   // [128][128]
    const float* __restrict__ entb,   // [128]
    const float* __restrict__ nwih,   // [512][128] (layer-1 wih)
    const float* __restrict__ nwhh,   // [2][512][128]
    const float* __restrict__ nbih,   // [2][512]
    const float* __restrict__ nbhh,   // [2][512]
    unsigned short* __restrict__ h0w,   // bf16 [160][64][128]
    unsigned short* __restrict__ X3,    // bf16 [4][160][512][16]
    unsigned short* __restrict__ nflat, // bf16 [10240][128]
    int* __restrict__ flag0, int* __restrict__ flag1)
{
  __shared__ __align__(16) unsigned short hA[2][16][136];   // L0/L1 state
  __shared__ __align__(16) unsigned short s_b[128][136];    // XG weights

  const int tid  = threadIdx.x;
  const int role = blockIdx.x >> 2;
  const int rb4  = blockIdx.x & 3;
  const int wv   = tid >> 6;
  const int lane = tid & 63;
  const int lo   = lane & 15;
  const int hi   = lane >> 4;

  if (role == 0) {
    // ======================= L0 =======================
    const int nb = rb4;
    const int u  = (wv << 4) | lo;

    short8 B0[4][4];
#pragma unroll
    for (int t = 0; t < 4; ++t) {
      const int n = t * 128 + u;
#pragma unroll
      for (int ks = 0; ks < 4; ++ks) {
        const float* src = nwhh + n * 128 + ks * 32 + hi * 8;
        short8 bfr;
#pragma unroll
        for (int jj = 0; jj < 8; ++jj) bfr[jj] = (short)f2b(src[jj]);
        B0[t][ks] = bfr;
      }
    }
    const float bi0 = nbih[u]       + nbhh[u];
    const float bf0 = nbih[128 + u] + nbhh[128 + u];
    const float bg0 = nbih[256 + u] + nbhh[256 + u];
    const float bo0 = nbih[384 + u] + nbhh[384 + u];

    {  // h_init = relu(gene @ entw^T + entb)
      const int q  = tid >> 5;
      const int u4 = (tid & 31) * 4;
      const float* gc = gene + (nb * 16 + q) * 128;
      float acc[4] = { entb[u4], entb[u4 + 1], entb[u4 + 2], entb[u4 + 3] };
      for (int qq = 0; qq < 32; ++qq) {
        const float4 gv = *(const float4*)&gc[qq * 4];
#pragma unroll
        for (int r = 0; r < 4; ++r) {
          const float4 wv2 = *(const float4*)&entw[(u4 + r) * 128 + qq * 4];
          acc[r] += gv.x * wv2.x + gv.y * wv2.y + gv.z * wv2.z + gv.w * wv2.w;
        }
      }
#pragma unroll
      for (int r = 0; r < 4; ++r)
        hA[0][q][u4 + r] = f2b(fmaxf(acc[r], 0.0f));
    }

    float c0[4] = {0.f, 0.f, 0.f, 0.f};
    __syncthreads();

    for (int c = 0; c < NCH; ++c) {
      for (int tt = 0; tt < CH; ++tt) {
        const int t  = c * CH + tt;
        const int rb = t & 1, wb = rb ^ 1;
        floatx4 a0 = {bi0, bi0, bi0, bi0};
        floatx4 a1 = {bf0, bf0, bf0, bf0};
        floatx4 a2 = {bg0, bg0, bg0, bg0};
        floatx4 a3 = {bo0, bo0, bo0, bo0};
        const unsigned short* ar = &hA[rb][lo][hi * 8];
#pragma unroll
        for (int ks = 0; ks < 4; ++ks) {
          const short8 afr = *(const short8*)(ar + ks * 32);
          a0 = __builtin_amdgcn_mfma_f32_16x16x32_bf16(afr, B0[0][ks], a0, 0, 0, 0);
          a1 = __builtin_amdgcn_mfma_f32_16x16x32_bf16(afr, B0[1][ks], a1, 0, 0, 0);
          a2 = __builtin_amdgcn_mfma_f32_16x16x32_bf16(afr, B0[2][ks], a2, 0, 0, 0);
          a3 = __builtin_amdgcn_mfma_f32_16x16x32_bf16(afr, B0[3][ks], a3, 0, 0, 0);
        }
        const size_t obase = (size_t)(t * 64 + nb * 16) * 128;
#pragma unroll
        for (int r = 0; r < 4; ++r) {
          const float iv = sgm(a0[r]);
          const float fv = sgm(a1[r]);
          const float gv = tanhf_(a2[r]);
          const float ov = sgm(a3[r]);
          const float cn = fv * c0[r] + iv * gv;
          c0[r] = cn;
          const unsigned short hb = f2b(ov * tanhf_(cn));
          const int q = hi * 4 + r;
          hA[wb][q][u] = hb;
          __builtin_nontemporal_store(hb, &h0w[obase + (size_t)q * 128 + u]);
        }
        if (tt < CH - 1) barrier_lds();
      }
      // chunk end: drain stores (syncthreads emits vmcnt(0)) + signal
      __syncthreads();
      if (tid == 0) {
        __threadfence();
        __hip_atomic_fetch_add(&flag0[c], 1, __ATOMIC_RELEASE,
                               __HIP_MEMORY_SCOPE_AGENT);
      }
    }

  } else if (role == 1) {
    // ======================= XG =======================
    const int xg = rb4;
    for (int i = tid; i < 128 * 32; i += 512) {
      const int nc = i >> 5, k4 = (i & 31) * 4;
      const float4 w = *(const float4*)&nwih[(size_t)(xg * 128 + nc) * 128 + k4];
      s_b[nc][k4]     = f2b(w.x);
      s_b[nc][k4 + 1] = f2b(w.y);
      s_b[nc][k4 + 2] = f2b(w.z);
      s_b[nc][k4 + 3] = f2b(w.w);
    }
    const int gg = wv & 3;       // gene-group
    const int ch = wv >> 2;      // col-half within this block's 128-col tile

    for (int c = 0; c < NCH; ++c) {
      if (tid == 0) {
        while (__hip_atomic_load(&flag0[c], __ATOMIC_ACQUIRE,
                                 __HIP_MEMORY_SCOPE_AGENT) < 4)
          __builtin_amdgcn_s_sleep(8);
        __threadfence();
      }
      __syncthreads();

      for (int tt = 0; tt < CH; ++tt) {
        const int t = c * CH + tt;
        floatx4 acc[4];
#pragma unroll
        for (int nt = 0; nt < 4; ++nt) acc[nt] = (floatx4){0.f, 0.f, 0.f, 0.f};
        const unsigned short* arow =
            h0w + (size_t)(t * 64 + gg * 16 + lo) * 128 + hi * 8;
#pragma unroll
        for (int ks = 0; ks < 4; ++ks) {
          const short8 afr = *(const short8*)(arow + ks * 32);
#pragma unroll
          for (int nt = 0; nt < 4; ++nt) {
            const short8 bfr =
                *(const short8*)&s_b[ch * 64 + nt * 16 + lo][ks * 32 + hi * 8];
            acc[nt] = __builtin_amdgcn_mfma_f32_16x16x32_bf16(afr, bfr, acc[nt], 0, 0, 0);
          }
        }
#pragma unroll
        for (int nt = 0; nt < 4; ++nt) {
          const size_t base3 =
              ((((size_t)gg * 160 + t) * 512) + xg * 128 + ch * 64 + nt * 16 + lo) * 16
              + hi * 4;
          short4v xv;
#pragma unroll
          for (int r = 0; r < 4; ++r) xv[r] = (short)f2b(acc[nt][r]);
          __builtin_nontemporal_store(xv, (short4v*)&X3[base3]);
        }
      }
      __syncthreads();   // drain stores across all waves
      if (tid == 0) {
        __threadfence();
        __hip_atomic_fetch_add(&flag1[c], 1, __ATOMIC_RELEASE,
                               __HIP_MEMORY_SCOPE_AGENT);
      }
    }

  } else {
    // ======================= L1 =======================
    const int nb = rb4;
    const int u  = (wv << 4) | lo;

    short8 B1[4][4];
#pragma unroll
    for (int t = 0; t < 4; ++t) {
      const int n = t * 128 + u;
#pragma unroll
      for (int ks = 0; ks < 4; ++ks) {
        const float* src = nwhh + 512 * 128 + n * 128 + ks * 32 + hi * 8;
        short8 bfr;
#pragma unroll
        for (int jj = 0; jj < 8; ++jj) bfr[jj] = (short)f2b(src[jj]);
        B1[t][ks] = bfr;
      }
    }
    const float bi1 = nbih[512 + u]       + nbhh[512 + u];
    const float bf1 = nbih[512 + 128 + u] + nbhh[512 + 128 + u];
    const float bg1 = nbih[512 + 256 + u] + nbhh[512 + 256 + u];
    const float bo1 = nbih[512 + 384 + u] + nbhh[512 + 384 + u];

    {  // h1_{-1} = relu(gene @ entw^T + entb), recomputed locally
      const int q  = tid >> 5;
      const int u4 = (tid & 31) * 4;
      const float* gc = gene + (nb * 16 + q) * 128;
      float acc[4] = { entb[u4], entb[u4 + 1], entb[u4 + 2], entb[u4 + 3] };
      for (int qq = 0; qq < 32; ++qq) {
        const float4 gv = *(const float4*)&gc[qq * 4];
#pragma unroll
        for (int r = 0; r < 4; ++r) {
          const float4 wv2 = *(const float4*)&entw[(u4 + r) * 128 + qq * 4];
          acc[r] += gv.x * wv2.x + gv.y * wv2.y + gv.z * wv2.z + gv.w * wv2.w;
        }
      }
#pragma unroll
      for (int r = 0; r < 4; ++r)
        hA[0][q][u4 + r] = f2b(fmaxf(acc[r], 0.0f));
    }

    float c1[4] = {0.f, 0.f, 0.f, 0.f};
    const size_t xstep = 512 * 16;
    const unsigned short* xb = X3 + ((size_t)nb * 160) * xstep
                             + (size_t)u * 16 + hi * 4;
    __syncthreads();

    for (int c = 0; c < NCH; ++c) {
      if (tid == 0) {
        while (__hip_atomic_load(&flag1[c], __ATOMIC_ACQUIRE,
                                 __HIP_MEMORY_SCOPE_AGENT) < 4)
          __builtin_amdgcn_s_sleep(8);
        __threadfence();
      }
      __syncthreads();

      // prefetch first step of chunk
      const unsigned short* xp = xb + (size_t)(c * CH) * xstep;
      short4v x0 = *(const short4v*)(xp);
      short4v x1 = *(const short4v*)(xp + 128 * 16);
      short4v x2 = *(const short4v*)(xp + 256 * 16);
      short4v x3 = *(const short4v*)(xp + 384 * 16);

      for (int tt = 0; tt < CH; ++tt) {
        const int t  = c * CH + tt;
        const int rb = t & 1, wb = rb ^ 1;

        floatx4 a0 = {bi1, bi1, bi1, bi1};
        floatx4 a1 = {bf1, bf1, bf1, bf1};
        floatx4 a2 = {bg1, bg1, bg1, bg1};
        floatx4 a3 = {bo1, bo1, bo1, bo1};
        const unsigned short* ar = &hA[rb][lo][hi * 8];
#pragma unroll
        for (int ks = 0; ks < 4; ++ks) {
          const short8 afr = *(const short8*)(ar + ks * 32);
          a0 = __builtin_amdgcn_mfma_f32_16x16x32_bf16(afr, B1[0][ks], a0, 0, 0, 0);
          a1 = __builtin_amdgcn_mfma_f32_16x16x32_bf16(afr, B1[1][ks], a1, 0, 0, 0);
          a2 = __builtin_amdgcn_mfma_f32_16x16x32_bf16(afr, B1[2][ks], a2, 0, 0, 0);
          a3 = __builtin_amdgcn_mfma_f32_16x16x32_bf16(afr, B1[3][ks], a3, 0, 0, 0);
        }

        const short4v cx0 = x0, cx1 = x1, cx2 = x2, cx3 = x3;
        if (tt + 1 < CH) {  // prefetch next step (same chunk -> flag covers it)
          const unsigned short* xn = xb + (size_t)(t + 1) * xstep;
          x0 = *(const short4v*)(xn);
          x1 = *(const short4v*)(xn + 128 * 16);
          x2 = *(const short4v*)(xn + 256 * 16);
          x3 = *(const short4v*)(xn + 384 * 16);
        }

        const size_t obase = (size_t)((159 - t) * 64 + nb * 16) * 128;
#pragma unroll
        for (int r = 0; r < 4; ++r) {
          const float iv = sgm(a0[r] + b2f((unsigned short)cx0[r]));
          const float fv = sgm(a1[r] + b2f((unsigned short)cx1[r]));
          const float gv = tanhf_(a2[r] + b2f((unsigned short)cx2[r]));
          const float ov = sgm(a3[r] + b2f((unsigned short)cx3[r]));
          const float cn = fv * c1[r] + iv * gv;
          c1[r] = cn;
          const unsigned short hb = f2b(ov * tanhf_(cn));
          const int q = hi * 4 + r;
          hA[wb][q][u] = hb;
          __builtin_nontemporal_store(hb, &nflat[obase + (size_t)q * 128 + u]);
        }
        barrier_lds();
      }
    }
  }
}

// ---------------------------------------------------------------------------
// Edge: unchanged from R10/R13. 640 blocks x 256 threads, snake-permuted.
// ---------------------------------------------------------------------------
__global__ __launch_bounds__(256, 1) void edge_kernel(
    const unsigned short* __restrict__ nflat, // bf16 [10240][128]
    const float* __restrict__ exw, const float* __restrict__ exb,   // [32][128],[32]
    const float* __restrict__ enw, const float* __restrict__ enb,   // [16][32],[16]
    const float* __restrict__ ewih,  // [1][64][16]
    const float* __restrict__ ewhh,  // [2][64][16]
    const float* __restrict__ ebih, const float* __restrict__ ebhh, // [2][64]
    const float* __restrict__ ee1w, const float* __restrict__ ee1b,
    const float* __restrict__ ee2w, const float* __restrict__ ee2b,
    const float* __restrict__ ef1w, const float* __restrict__ ef1b,
    const float* __restrict__ ef2w, const float* __restrict__ ef2b,
    float* __restrict__ out)
{
  const int tid = threadIdx.x;
  const int sg  = tid >> 4;
  const int u   = tid & 15;
  const int b   = blockIdx.x;

  const int row = b >> 8, r = b & 255;
  const int bb  = (row == 1) ? (511 - r) : ((row << 8) + r);
  const int kbase = bb * 16;
  const int jrow  = 160 - (bb >> 2);
  const int gid   = (kbase & 63) + sg;

  __shared__ __align__(16) float s_nf[16][132];
  __shared__ float s_w0s[64][17];
  __shared__ float s_was[64][17];
  __shared__ float s_wbs[64][17];
  __shared__ float s_wh[16][17];
  __shared__ float s_ef2[32][10];
  __shared__ __align__(16) float s_ee2[16];
  __shared__ __align__(16) float t1b[16][12];
  __shared__ __align__(16) float t2b[16][12];
  __shared__ __align__(16) float x32[16][36];

  for (int i = tid; i < 16 * 128; i += 256)
    s_nf[i >> 7][i & 127] = b2f(nflat[(size_t)(kbase + (i >> 7)) * 128 + (i & 127)]);
  for (int i = tid; i < 64 * 16; i += 256) {
    s_w0s[i >> 4][i & 15] = ewhh[i];
    s_was[i >> 4][i & 15] = ewih[i];
    s_wbs[i >> 4][i & 15] = ewhh[1024 + i];
  }
  for (int i = tid; i < 8 * 16; i += 256) {
    s_wh[i >> 4][i & 15]       = ee1w[i];
    s_wh[8 + (i >> 4)][i & 15] = ef1w[i];
  }
  for (int i = tid; i < 32 * 8; i += 256) s_ef2[i >> 3][i & 7] = ef2w[i];
  if (tid < 16) s_ee2[tid] = ee2w[tid];

  if (b < NG) {
    for (int d = tid; d < NMAX; d += 256) {
      out[(size_t)b * (NMAX * NMAX) + (size_t)d * NMAX + d] = 0.0f;
      float* fb = out + (size_t)NG * NMAX * NMAX
                + ((size_t)b * NMAX * NMAX + (size_t)d * NMAX + d) * 16;
#pragma unroll
      for (int q = 0; q < 16; ++q) fb[q] = 0.0f;
    }
  }

  const float be0i = ebih[u]      + ebhh[u];
  const float be0f = ebih[16 + u] + ebhh[16 + u];
  const float be0g = ebih[32 + u] + ebhh[32 + u];
  const float be0o = ebih[48 + u] + ebhh[48 + u];
  const float be1i = ebih[64 + u]      + ebhh[64 + u];
  const float be1f = ebih[64 + 16 + u] + ebhh[64 + 16 + u];
  const float be1g = ebih[64 + 32 + u] + ebhh[64 + 32 + u];
  const float be1o = ebih[64 + 48 + u] + ebhh[64 + 48 + u];
  const float hbias = (u < 8) ? ee1b[u] : ef1b[u - 8];
  const float f2bl = ef2b[u], f2bu = ef2b[16 + u];
  const float e2bias = (u < 2) ? ee2b[u] : 0.0f;

  __syncthreads();

  half2v W0h[4][8], WAh[4][8], WBh[4][8], WHh[8];
#pragma unroll
  for (int g = 0; g < 4; ++g) {
    const int rw = g * 16 + u;
#pragma unroll
    for (int j = 0; j < 8; ++j) {
      const int v0 = (u + 2 * j) & 15, v1 = (u + 2 * j + 1) & 15;
      W0h[g][j] = pkh(s_w0s[rw][v0], s_w0s[rw][v1]);
      WAh[g][j] = pkh(s_was[rw][v0], s_was[rw][v1]);
      WBh[g][j] = pkh(s_wbs[rw][v0], s_wbs[rw][v1]);
    }
  }
#pragma unroll
  for (int j = 0; j < 8; ++j) {
    const int v0 = (u + 2 * j) & 15, v1 = (u + 2 * j + 1) & 15;
    WHh[j] = pkh(s_wh[u][v0], s_wh[u][v1]);
  }

  {
    float acc0 = exb[u], acc1 = exb[16 + u];
    const float* w0p = exw + u * 128;
    const float* w1p = exw + (16 + u) * 128;
    for (int qq = 0; qq < 32; ++qq) {
      const float4 nv  = *(const float4*)&s_nf[sg][qq * 4];
      const float4 w0v = *(const float4*)&w0p[qq * 4];
      const float4 w1v = *(const float4*)&w1p[qq * 4];
      acc0 += nv.x * w0v.x + nv.y * w0v.y + nv.z * w0v.z + nv.w * w0v.w;
      acc1 += nv.x * w1v.x + nv.y * w1v.y + nv.z * w1v.z + nv.w * w1v.w;
    }
    x32[sg][u] = fmaxf(acc0, 0.0f);
    x32[sg][16 + u] = fmaxf(acc1, 0.0f);
  }
  __builtin_amdgcn_wave_barrier();
  float c0 = 0.0f, c1 = 0.0f;
  half2v h20[8], h21[8];
  {
    float acc = enb[u];
    const float* ewp = enw + u * 32;
#pragma unroll
    for (int qq = 0; qq < 8; ++qq) {
      const float4 xv  = *(const float4*)&x32[sg][qq * 4];
      const float4 wv2 = *(const float4*)&ewp[qq * 4];
      acc += xv.x * wv2.x + xv.y * wv2.y + xv.z * wv2.z + xv.w * wv2.w;
    }
    const float h0e = fmaxf(acc, 0.0f);
    rotpack(h0e, h20);
#pragma unroll
    for (int j = 0; j < 8; ++j) h21[j] = h20[j];
  }

  float* exi = out + (size_t)gid * (NMAX * NMAX);
  float* fea = out + (size_t)NG * NMAX * NMAX + (size_t)gid * (NMAX * NMAX) * 16;
  const int jN = jrow * NMAX;

  for (int s = 0; s <= jrow; ++s) {
    const bool doStep = (s < jrow);
    const bool doHead = (s > 0);

    float a0, a1, a2, a3;
    if (doStep) {
      a0 = be0i; a1 = be0f; a2 = be0g; a3 = be0o;
#pragma unroll
      for (int j = 0; j < 8; ++j) {
        a0 = __builtin_amdgcn_fdot2(h20[j], W0h[0][j], a0, false);
        a1 = __builtin_amdgcn_fdot2(h20[j], W0h[1][j], a1, false);
        a2 = __builtin_amdgcn_fdot2(h20[j], W0h[2][j], a2, false);
        a3 = __builtin_amdgcn_fdot2(h20[j], W0h[3][j], a3, false);
      }
    }

    if (doHead) {
      __builtin_amdgcn_wave_barrier();
      const int sm = s - 1;
      const float2 ta0 = *(const float2*)&t2b[sg][0];
      const float2 ta1 = *(const float2*)&t2b[sg][2];
      const float2 ta2 = *(const float2*)&t2b[sg][4];
      const float2 ta3 = *(const float2*)&t2b[sg][6];
      const float2 wl0 = *(const float2*)&s_ef2[u][0];
      const float2 wl1 = *(const float2*)&s_ef2[u][2];
      const float2 wl2 = *(const float2*)&s_ef2[u][4];
      const float2 wl3 = *(const float2*)&s_ef2[u][6];
      const float2 wu0 = *(const float2*)&s_ef2[16 + u][0];
      const float2 wu1 = *(const float2*)&s_ef2[16 + u][2];
      const float2 wu2 = *(const float2*)&s_ef2[16 + u][4];
      const float2 wu3 = *(const float2*)&s_ef2[16 + u][6];
      const float fl = f2bl
          + ta0.x * wl0.x + ta0.y * wl0.y + ta1.x * wl1.x + ta1.y * wl1.y
          + ta2.x * wl2.x + ta2.y * wl2.y + ta3.x * wl3.x + ta3.y * wl3.y;
      const float fu = f2bu
          + ta0.x * wu0.x + ta0.y * wu0.y + ta1.x * wu1.x + ta1.y * wu1.y
          + ta2.x * wu2.x + ta2.y * wu2.y + ta3.x * wu3.x + ta3.y * wu3.y;
      fea[((size_t)jN + sm) * 16 + u] = fl;
      fea[((size_t)sm * NMAX + jrow) * 16 + u] = fu;
      if (u < 2) {
        const float4 t1a = *(const float4*)&t1b[sg][0];
        const float4 t1c = *(const float4*)&t1b[sg][4];
        const float4 we0 = *(const float4*)&s_ee2[u * 8];
        const float4 we1 = *(const float4*)&s_ee2[u * 8 + 4];
        float e = e2bias
            + t1a.x * we0.x + t1a.y * we0.y + t1a.z * we0.z + t1a.w * we0.w
            + t1c.x * we1.x + t1c.y * we1.y + t1c.z * we1.z + t1c.w * we1.w;
        const size_t idx = (u == 0) ? ((size_t)jN + sm)
                                    : ((size_t)sm * NMAX + jrow);
        exi[idx] = sgm(e);
      }
    }

    if (doStep) {
      {
        const float iv = sgm(a0), fv = sgm(a1), gv = tanhf_(a2), ov = sgm(a3);
        c0 = fv * c0 + iv * gv;
        rotpack(ov * tanhf_(c0), h20);
      }
      float b0 = be1i, b1 = be1f, b2 = be1g, b3 = be1o;
#pragma unroll
      for (int j = 0; j < 8; ++j) {
        b0 = __builtin_amdgcn_fdot2(h20[j], WAh[0][j], b0, false);
        b1 = __builtin_amdgcn_fdot2(h20[j], WAh[1][j], b1, false);
        b2 = __builtin_amdgcn_fdot2(h20[j], WAh[2][j], b2, false);
        b3 = __builtin_amdgcn_fdot2(h20[j], WAh[3][j], b3, false);
      }
#pragma unroll
      for (int j = 0; j < 8; ++j) {
        b0 = __builtin_amdgcn_fdot2(h21[j], WBh[0][j], b0, false);
        b1 = __builtin_amdgcn_fdot2(h21[j], WBh[1][j], b1, false);
        b2 = __builtin_amdgcn_fdot2(h21[j], WBh[2][j], b2, false);
        b3 = __builtin_amdgcn_fdot2(h21[j], WBh[3][j], b3, false);
      }
      {
        const float iv = sgm(b0), fv = sgm(b1), gv = tanhf_(b2), ov = sgm(b3);
        c1 = fv * c1 + iv * gv;
        rotpack(ov * tanhf_(c1), h21);
      }
      {
        float th = hbias;
#pragma unroll
        for (int j = 0; j < 8; ++j)
          th = __builtin_amdgcn_fdot2(h21[j], WHh[j], th, false);
        th = fmaxf(th, 0.0f);
        if (u < 8) t1b[sg][u] = th; else t2b[sg][u - 8] = th;
      }
      __builtin_amdgcn_wave_barrier();
    }
  }
}

extern "C" void kernel_launch(void* const* d_in, const int* in_sizes, int n_in,
                              void* d_out, int out_size, void* d_ws, size_t ws_size,
                              hipStream_t stream) {
  (void)in_sizes; (void)n_in; (void)out_size; (void)ws_size;
  const float* gene = (const float*)d_in[0];
  const float* entw = (const float*)d_in[1];
  const float* entb = (const float*)d_in[2];
  const float* nwih = (const float*)d_in[4];
  const float* nwhh = (const float*)d_in[5];
  const float* nbih = (const float*)d_in[6];
  const float* nbhh = (const float*)d_in[7];
  const float* exw  = (const float*)d_in[8];
  const float* exb  = (const float*)d_in[9];
  const float* enw  = (const float*)d_in[10];
  const float* enb  = (const float*)d_in[11];
  const float* ewih = (const float*)d_in[13];
  const float* ewhh = (const float*)d_in[14];
  const float* ebih = (const float*)d_in[15];
  const float* ebhh = (const float*)d_in[16];
  const float* ee1w = (const float*)d_in[17];
  const float* ee1b = (const float*)d_in[18];
  const float* ee2w = (const float*)d_in[19];
  const float* ee2b = (const float*)d_in[20];
  const float* ef1w = (const float*)d_in[21];
  const float* ef1b = (const float*)d_in[22];
  const float* ef2w = (const float*)d_in[23];
  const float* ef2b = (const float*)d_in[24];

  // ws layout (bytes):
  //   nflat @ 0         : 10240*128*2 = 2,621,440
  //   h0w   @ 2621440   : 160*64*128*2 = 2,621,440
  //   flags @ 5242880   : flag0[NCH]; flag1 at +4096
  //   X3    @ 5259264   : 4*160*512*16*2 = 10,485,760
  char* ws = (char*)d_ws;
  unsigned short* nflat = (unsigned short*)(ws);
  unsigned short* h0w   = (unsigned short*)(ws + 2621440);
  int* flag0            = (int*)(ws + 5242880);
  int* flag1            = (int*)(ws + 5242880 + 4096);
  unsigned short* X3    = (unsigned short*)(ws + 5259264);

  hipMemsetAsync(ws + 5242880, 0, 8192, stream);
  node_fused<<<12, 512, 0, stream>>>(gene, entw, entb, nwih, nwhh, nbih, nbhh,
                                     h0w, X3, nflat, flag0, flag1);
  edge_kernel<<<640, 256, 0, stream>>>(nflat, exw, exb, enw, enb, ewih, ewhh,
                                       ebih, ebhh, ee1w, ee1b, ee2w, ee2b,
                                       ef1w, ef1b, ef2w, ef2b, (float*)d_out);
}

// Round 16
// 456.418 us; speedup vs baseline: 1.0070x; 1.0070x over previous
//
#include <hip/hip_runtime.h>

// GraphGenRnn — R16: X-GEMM folded INTO the L0 blocks (X[t] rows are
// gene-local: block nb computes X for its 16 genes straight from the h0_t in
// its own LDS, wih1 staged in LDS bf16). Removes the XG pipeline stage, the
// h0w global round-trip, and one cross-XCD handoff per chunk. Blocks 0-3 =
// L0+X, 8-11 = L1 (one chunk behind, per-pair monotonic flag), 4-7 exit.
// Chunked sync (CH=16) as in R14. Edge kernel unchanged (R10 structure).

typedef __attribute__((ext_vector_type(8))) short short8;
typedef __attribute__((ext_vector_type(4))) short short4v;
typedef __attribute__((ext_vector_type(4))) float floatx4;
typedef _Float16 half2v __attribute__((ext_vector_type(2)));

#define NG 64
#define NMAX 161
#define CH 16
#define NCH 10

__device__ __forceinline__ float sgm(float x) {
  return __builtin_amdgcn_rcpf(1.0f + __expf(-x));
}
__device__ __forceinline__ float tanhf_(float x) {
  return 2.0f * __builtin_amdgcn_rcpf(1.0f + __expf(-2.0f * x)) - 1.0f;
}
__device__ __forceinline__ unsigned short f2b(float x) {
  union { float f; unsigned u; } v; v.f = x;
  unsigned r = v.u + 0x7fffu + ((v.u >> 16) & 1u);   // RNE to bf16
  return (unsigned short)(r >> 16);
}
__device__ __forceinline__ float b2f(unsigned short h) {
  union { unsigned u; float f; } v; v.u = ((unsigned)h) << 16; return v.f;
}
__device__ __forceinline__ half2v pkh(float a, float b) {
  return __builtin_bit_cast(half2v, __builtin_amdgcn_cvt_pkrtz(a, b));
}
// barrier that orders LDS only (no vmcnt drain of in-flight global stores)
__device__ __forceinline__ void barrier_lds() {
  asm volatile("s_waitcnt lgkmcnt(0)" ::: "memory");
  __builtin_amdgcn_s_barrier();
}

// DPP row_ror:N within 16-lane rows: out[i] = in[(i+N)&15]
#define RORF(x, N) __builtin_bit_cast(float, __builtin_amdgcn_update_dpp(      \
    __builtin_bit_cast(int, (x)), __builtin_bit_cast(int, (x)),                \
    0x120 | (N), 0xF, 0xF, false))

__device__ __forceinline__ void rotpack(float h, half2v* out) {
  const float r1  = RORF(h, 1),  r2  = RORF(h, 2),  r3  = RORF(h, 3);
  const float r4  = RORF(h, 4),  r5  = RORF(h, 5),  r6  = RORF(h, 6);
  const float r7  = RORF(h, 7),  r8  = RORF(h, 8),  r9  = RORF(h, 9);
  const float r10 = RORF(h, 10), r11 = RORF(h, 11), r12 = RORF(h, 12);
  const float r13 = RORF(h, 13), r14 = RORF(h, 14), r15 = RORF(h, 15);
  out[0] = pkh(h,   r1);
  out[1] = pkh(r2,  r3);
  out[2] = pkh(r4,  r5);
  out[3] = pkh(r6,  r7);
  out[4] = pkh(r8,  r9);
  out[5] = pkh(r10, r11);
  out[6] = pkh(r12, r13);
  out[7] = pkh(r14, r15);
}

// ---------------------------------------------------------------------------
// node_fused: 12 blocks x 512 threads.
//   blocks 0-3 (L0X): L0 recurrence for genes [16nb,16nb+16) + X-GEMM for the
//     same genes (wih1 in LDS bf16). X stores regular -> L2/L3. Signals
//     flag[nb] (monotonic chunk counter).
//   blocks 4-7: exit.
//   blocks 8-11 (L1): L1 recurrence, waits flag[nb] >= c+1, reads X3.
// ---------------------------------------------------------------------------
__global__ __launch_bounds__(512) void node_fused(
    const float* __restrict__ gene,   // [64][128]
    const float* __restrict__ entw,   // [128][128]
    const float* __restrict__ entb,   // [128]
    const float* __restrict__ nwih,   // [512][128] (layer-1 wih)
    const float* __restrict__ nwhh,   // [2][512][128]
    const float* __restrict__ nbih,   // [2][512]
    const float* __restrict__ nbhh,   // [2][512]
    unsigned short* __restrict__ X3,    // bf16 [4][160][512][16]
    unsigned short* __restrict__ nflat, // bf16 [10240][128]
    int* __restrict__ flagP)
{
  const int tid  = threadIdx.x;
  const int role = blockIdx.x >> 2;
  const int nb   = blockIdx.x & 3;
  const int wv   = tid >> 6;
  const int lane = tid & 63;
  const int lo   = lane & 15;
  const int hi   = lane >> 4;

  if (role == 1) return;   // blocks 4-7 unused

  __shared__ __align__(16) unsigned short hA[2][16][136];

  if (role == 0) {
    // ======================= L0 + X =======================
    __shared__ __align__(16) unsigned short s_wih[512][136];  // 139 KB
    const int u = (wv << 4) | lo;

    // stage wih1 as bf16 (row = output col, padded)
    for (int i = tid; i < 512 * 32; i += 512) {
      const int nc = i >> 5, k4 = (i & 31) * 4;
      const float4 w = *(const float4*)&nwih[(size_t)nc * 128 + k4];
      s_wih[nc][k4]     = f2b(w.x);
      s_wih[nc][k4 + 1] = f2b(w.y);
      s_wih[nc][k4 + 2] = f2b(w.z);
      s_wih[nc][k4 + 3] = f2b(w.w);
    }

    short8 B0[4][4];
#pragma unroll
    for (int t = 0; t < 4; ++t) {
      const int n = t * 128 + u;
#pragma unroll
      for (int ks = 0; ks < 4; ++ks) {
        const float* src = nwhh + n * 128 + ks * 32 + hi * 8;
        short8 bfr;
#pragma unroll
        for (int jj = 0; jj < 8; ++jj) bfr[jj] = (short)f2b(src[jj]);
        B0[t][ks] = bfr;
      }
    }
    const float bi0 = nbih[u]       + nbhh[u];
    const float bf0 = nbih[128 + u] + nbhh[128 + u];
    const float bg0 = nbih[256 + u] + nbhh[256 + u];
    const float bo0 = nbih[384 + u] + nbhh[384 + u];

    {  // h_init = relu(gene @ entw^T + entb)
      const int q  = tid >> 5;
      const int u4 = (tid & 31) * 4;
      const float* gc = gene + (nb * 16 + q) * 128;
      float acc[4] = { entb[u4], entb[u4 + 1], entb[u4 + 2], entb[u4 + 3] };
      for (int qq = 0; qq < 32; ++qq) {
        const float4 gv = *(const float4*)&gc[qq * 4];
#pragma unroll
        for (int r = 0; r < 4; ++r) {
          const float4 wv2 = *(const float4*)&entw[(u4 + r) * 128 + qq * 4];
          acc[r] += gv.x * wv2.x + gv.y * wv2.y + gv.z * wv2.z + gv.w * wv2.w;
        }
      }
#pragma unroll
      for (int r = 0; r < 4; ++r)
        hA[0][q][u4 + r] = f2b(fmaxf(acc[r], 0.0f));
    }

    float c0[4] = {0.f, 0.f, 0.f, 0.f};
    __syncthreads();

    for (int c = 0; c < NCH; ++c) {
      for (int tt = 0; tt < CH; ++tt) {
        const int t  = c * CH + tt;
        const int rb = t & 1, wb = rb ^ 1;
        // ---- L0 recurrence ----
        floatx4 a0 = {bi0, bi0, bi0, bi0};
        floatx4 a1 = {bf0, bf0, bf0, bf0};
        floatx4 a2 = {bg0, bg0, bg0, bg0};
        floatx4 a3 = {bo0, bo0, bo0, bo0};
        const unsigned short* ar = &hA[rb][lo][hi * 8];
#pragma unroll
        for (int ks = 0; ks < 4; ++ks) {
          const short8 afr = *(const short8*)(ar + ks * 32);
          a0 = __builtin_amdgcn_mfma_f32_16x16x32_bf16(afr, B0[0][ks], a0, 0, 0, 0);
          a1 = __builtin_amdgcn_mfma_f32_16x16x32_bf16(afr, B0[1][ks], a1, 0, 0, 0);
          a2 = __builtin_amdgcn_mfma_f32_16x16x32_bf16(afr, B0[2][ks], a2, 0, 0, 0);
          a3 = __builtin_amdgcn_mfma_f32_16x16x32_bf16(afr, B0[3][ks], a3, 0, 0, 0);
        }
#pragma unroll
        for (int r = 0; r < 4; ++r) {
          const float iv = sgm(a0[r]);
          const float fv = sgm(a1[r]);
          const float gv = tanhf_(a2[r]);
          const float ov = sgm(a3[r]);
          const float cn = fv * c0[r] + iv * gv;
          c0[r] = cn;
          hA[wb][hi * 4 + r][u] = f2b(ov * tanhf_(cn));
        }
        barrier_lds();   // h0_t visible to all waves
        // ---- X-GEMM on fresh h0_t: wave wv covers cols [64wv, 64wv+64) ----
        const unsigned short* axr = &hA[wb][lo][hi * 8];
        const size_t xrow = ((size_t)(nb * 160 + t)) * (512 * 16);
#pragma unroll
        for (int ct = 0; ct < 4; ++ct) {
          const int colb = (wv * 4 + ct) * 16;
          floatx4 xa = {0.f, 0.f, 0.f, 0.f};
#pragma unroll
          for (int ks = 0; ks < 4; ++ks) {
            const short8 afr = *(const short8*)(axr + ks * 32);
            const short8 bfr = *(const short8*)&s_wih[colb + lo][ks * 32 + hi * 8];
            xa = __builtin_amdgcn_mfma_f32_16x16x32_bf16(afr, bfr, xa, 0, 0, 0);
          }
          short4v xv;
#pragma unroll
          for (int r = 0; r < 4; ++r) xv[r] = (short)f2b(xa[r]);
          *(short4v*)&X3[xrow + (size_t)(colb + lo) * 16 + hi * 4] = xv;
        }
      }
      // chunk end: drain X stores + signal pair flag
      __syncthreads();
      if (tid == 0) {
        __threadfence();
        __hip_atomic_fetch_add(&flagP[nb], 1, __ATOMIC_RELEASE,
                               __HIP_MEMORY_SCOPE_AGENT);
      }
    }

  } else {
    // ======================= L1 =======================
    const int u = (wv << 4) | lo;

    short8 B1[4][4];
#pragma unroll
    for (int t = 0; t < 4; ++t) {
      const int n = t * 128 + u;
#pragma unroll
      for (int ks = 0; ks < 4; ++ks) {
        const float* src = nwhh + 512 * 128 + n * 128 + ks * 32 + hi * 8;
        short8 bfr;
#pragma unroll
        for (int jj = 0; jj < 8; ++jj) bfr[jj] = (short)f2b(src[jj]);
        B1[t][ks] = bfr;
      }
    }
    const float bi1 = nbih[512 + u]       + nbhh[512 + u];
    const float bf1 = nbih[512 + 128 + u] + nbhh[512 + 128 + u];
    const float bg1 = nbih[512 + 256 + u] + nbhh[512 + 256 + u];
    const float bo1 = nbih[512 + 384 + u] + nbhh[512 + 384 + u];

    {  // h1_{-1} = relu(gene @ entw^T + entb), recomputed locally
      const int q  = tid >> 5;
      const int u4 = (tid & 31) * 4;
      const float* gc = gene + (nb * 16 + q) * 128;
      float acc[4] = { entb[u4], entb[u4 + 1], entb[u4 + 2], entb[u4 + 3] };
      for (int qq = 0; qq < 32; ++qq) {
        const float4 gv = *(const float4*)&gc[qq * 4];
#pragma unroll
        for (int r = 0; r < 4; ++r) {
          const float4 wv2 = *(const float4*)&entw[(u4 + r) * 128 + qq * 4];
          acc[r] += gv.x * wv2.x + gv.y * wv2.y + gv.z * wv2.z + gv.w * wv2.w;
        }
      }
#pragma unroll
      for (int r = 0; r < 4; ++r)
        hA[0][q][u4 + r] = f2b(fmaxf(acc[r], 0.0f));
    }

    float c1[4] = {0.f, 0.f, 0.f, 0.f};
    const size_t xstep = 512 * 16;
    const unsigned short* xb = X3 + ((size_t)nb * 160) * xstep
                             + (size_t)u * 16 + hi * 4;
    __syncthreads();

    for (int c = 0; c < NCH; ++c) {
      if (tid == 0) {
        while (__hip_atomic_load(&flagP[nb], __ATOMIC_ACQUIRE,
                                 __HIP_MEMORY_SCOPE_AGENT) < c + 1)
          __builtin_amdgcn_s_sleep(8);
        __threadfence();
      }
      __syncthreads();

      // prefetch first step of chunk
      const unsigned short* xp = xb + (size_t)(c * CH) * xstep;
      short4v x0 = *(const short4v*)(xp);
      short4v x1 = *(const short4v*)(xp + 128 * 16);
      short4v x2 = *(const short4v*)(xp + 256 * 16);
      short4v x3 = *(const short4v*)(xp + 384 * 16);

      for (int tt = 0; tt < CH; ++tt) {
        const int t  = c * CH + tt;
        const int rb = t & 1, wb = rb ^ 1;

        floatx4 a0 = {bi1, bi1, bi1, bi1};
        floatx4 a1 = {bf1, bf1, bf1, bf1};
        floatx4 a2 = {bg1, bg1, bg1, bg1};
        floatx4 a3 = {bo1, bo1, bo1, bo1};
        const unsigned short* ar = &hA[rb][lo][hi * 8];
#pragma unroll
        for (int ks = 0; ks < 4; ++ks) {
          const short8 afr = *(const short8*)(ar + ks * 32);
          a0 = __builtin_amdgcn_mfma_f32_16x16x32_bf16(afr, B1[0][ks], a0, 0, 0, 0);
          a1 = __builtin_amdgcn_mfma_f32_16x16x32_bf16(afr, B1[1][ks], a1, 0, 0, 0);
          a2 = __builtin_amdgcn_mfma_f32_16x16x32_bf16(afr, B1[2][ks], a2, 0, 0, 0);
          a3 = __builtin_amdgcn_mfma_f32_16x16x32_bf16(afr, B1[3][ks], a3, 0, 0, 0);
        }

        const short4v cx0 = x0, cx1 = x1, cx2 = x2, cx3 = x3;
        if (tt + 1 < CH) {
          const unsigned short* xn = xb + (size_t)(t + 1) * xstep;
          x0 = *(const short4v*)(xn);
          x1 = *(const short4v*)(xn + 128 * 16);
          x2 = *(const short4v*)(xn + 256 * 16);
          x3 = *(const short4v*)(xn + 384 * 16);
        }

        const size_t obase = (size_t)((159 - t) * 64 + nb * 16) * 128;
#pragma unroll
        for (int r = 0; r < 4; ++r) {
          const float iv = sgm(a0[r] + b2f((unsigned short)cx0[r]));
          const float fv = sgm(a1[r] + b2f((unsigned short)cx1[r]));
          const float gv = tanhf_(a2[r] + b2f((unsigned short)cx2[r]));
          const float ov = sgm(a3[r] + b2f((unsigned short)cx3[r]));
          const float cn = fv * c1[r] + iv * gv;
          c1[r] = cn;
          const unsigned short hb = f2b(ov * tanhf_(cn));
          const int q = hi * 4 + r;
          hA[wb][q][u] = hb;
          nflat[obase + (size_t)q * 128 + u] = hb;
        }
        barrier_lds();
      }
    }
  }
}

// ---------------------------------------------------------------------------
// Edge: unchanged from R10/R14. 640 blocks x 256 threads, snake-permuted.
// ---------------------------------------------------------------------------
__global__ __launch_bounds__(256, 1) void edge_kernel(
    const unsigned short* __restrict__ nflat, // bf16 [10240][128]
    const float* __restrict__ exw, const float* __restrict__ exb,   // [32][128],[32]
    const float* __restrict__ enw, const float* __restrict__ enb,   // [16][32],[16]
    const float* __restrict__ ewih,  // [1][64][16]
    const float* __restrict__ ewhh,  // [2][64][16]
    const float* __restrict__ ebih, const float* __restrict__ ebhh, // [2][64]
    const float* __restrict__ ee1w, const float* __restrict__ ee1b,
    const float* __restrict__ ee2w, const float* __restrict__ ee2b,
    const float* __restrict__ ef1w, const float* __restrict__ ef1b,
    const float* __restrict__ ef2w, const float* __restrict__ ef2b,
    float* __restrict__ out)
{
  const int tid = threadIdx.x;
  const int sg  = tid >> 4;
  const int u   = tid & 15;
  const int b   = blockIdx.x;

  const int row = b >> 8, r = b & 255;
  const int bb  = (row == 1) ? (511 - r) : ((row << 8) + r);
  const int kbase = bb * 16;
  const int jrow  = 160 - (bb >> 2);
  const int gid   = (kbase & 63) + sg;

  __shared__ __align__(16) float s_nf[16][132];
  __shared__ float s_w0s[64][17];
  __shared__ float s_was[64][17];
  __shared__ float s_wbs[64][17];
  __shared__ float s_wh[16][17];
  __shared__ float s_ef2[32][10];
  __shared__ __align__(16) float s_ee2[16];
  __shared__ __align__(16) float t1b[16][12];
  __shared__ __align__(16) float t2b[16][12];
  __shared__ __align__(16) float x32[16][36];

  for (int i = tid; i < 16 * 128; i += 256)
    s_nf[i >> 7][i & 127] = b2f(nflat[(size_t)(kbase + (i >> 7)) * 128 + (i & 127)]);
  for (int i = tid; i < 64 * 16; i += 256) {
    s_w0s[i >> 4][i & 15] = ewhh[i];
    s_was[i >> 4][i & 15] = ewih[i];
    s_wbs[i >> 4][i & 15] = ewhh[1024 + i];
  }
  for (int i = tid; i < 8 * 16; i += 256) {
    s_wh[i >> 4][i & 15]       = ee1w[i];
    s_wh[8 + (i >> 4)][i & 15] = ef1w[i];
  }
  for (int i = tid; i < 32 * 8; i += 256) s_ef2[i >> 3][i & 7] = ef2w[i];
  if (tid < 16) s_ee2[tid] = ee2w[tid];

  if (b < NG) {
    for (int d = tid; d < NMAX; d += 256) {
      out[(size_t)b * (NMAX * NMAX) + (size_t)d * NMAX + d] = 0.0f;
      float* fb = out + (size_t)NG * NMAX * NMAX
                + ((size_t)b * NMAX * NMAX + (size_t)d * NMAX + d) * 16;
#pragma unroll
      for (int q = 0; q < 16; ++q) fb[q] = 0.0f;
    }
  }

  const float be0i = ebih[u]      + ebhh[u];
  const float be0f = ebih[16 + u] + ebhh[16 + u];
  const float be0g = ebih[32 + u] + ebhh[32 + u];
  const float be0o = ebih[48 + u] + ebhh[48 + u];
  const float be1i = ebih[64 + u]      + ebhh[64 + u];
  const float be1f = ebih[64 + 16 + u] + ebhh[64 + 16 + u];
  const float be1g = ebih[64 + 32 + u] + ebhh[64 + 32 + u];
  const float be1o = ebih[64 + 48 + u] + ebhh[64 + 48 + u];
  const float hbias = (u < 8) ? ee1b[u] : ef1b[u - 8];
  const float f2bl = ef2b[u], f2bu = ef2b[16 + u];
  const float e2bias = (u < 2) ? ee2b[u] : 0.0f;

  __syncthreads();

  half2v W0h[4][8], WAh[4][8], WBh[4][8], WHh[8];
#pragma unroll
  for (int g = 0; g < 4; ++g) {
    const int rw = g * 16 + u;
#pragma unroll
    for (int j = 0; j < 8; ++j) {
      const int v0 = (u + 2 * j) & 15, v1 = (u + 2 * j + 1) & 15;
      W0h[g][j] = pkh(s_w0s[rw][v0], s_w0s[rw][v1]);
      WAh[g][j] = pkh(s_was[rw][v0], s_was[rw][v1]);
      WBh[g][j] = pkh(s_wbs[rw][v0], s_wbs[rw][v1]);
    }
  }
#pragma unroll
  for (int j = 0; j < 8; ++j) {
    const int v0 = (u + 2 * j) & 15, v1 = (u + 2 * j + 1) & 15;
    WHh[j] = pkh(s_wh[u][v0], s_wh[u][v1]);
  }

  {
    float acc0 = exb[u], acc1 = exb[16 + u];
    const float* w0p = exw + u * 128;
    const float* w1p = exw + (16 + u) * 128;
    for (int qq = 0; qq < 32; ++qq) {
      const float4 nv  = *(const float4*)&s_nf[sg][qq * 4];
      const float4 w0v = *(const float4*)&w0p[qq * 4];
      const float4 w1v = *(const float4*)&w1p[qq * 4];
      acc0 += nv.x * w0v.x + nv.y * w0v.y + nv.z * w0v.z + nv.w * w0v.w;
      acc1 += nv.x * w1v.x + nv.y * w1v.y + nv.z * w1v.z + nv.w * w1v.w;
    }
    x32[sg][u] = fmaxf(acc0, 0.0f);
    x32[sg][16 + u] = fmaxf(acc1, 0.0f);
  }
  __builtin_amdgcn_wave_barrier();
  float c0 = 0.0f, c1 = 0.0f;
  half2v h20[8], h21[8];
  {
    float acc = enb[u];
    const float* ewp = enw + u * 32;
#pragma unroll
    for (int qq = 0; qq < 8; ++qq) {
      const float4 xv  = *(const float4*)&x32[sg][qq * 4];
      const float4 wv2 = *(const float4*)&ewp[qq * 4];
      acc += xv.x * wv2.x + xv.y * wv2.y + xv.z * wv2.z + xv.w * wv2.w;
    }
    const float h0e = fmaxf(acc, 0.0f);
    rotpack(h0e, h20);
#pragma unroll
    for (int j = 0; j < 8; ++j) h21[j] = h20[j];
  }

  float* exi = out + (size_t)gid * (NMAX * NMAX);
  float* fea = out + (size_t)NG * NMAX * NMAX + (size_t)gid * (NMAX * NMAX) * 16;
  const int jN = jrow * NMAX;

  for (int s = 0; s <= jrow; ++s) {
    const bool doStep = (s < jrow);
    const bool doHead = (s > 0);

    float a0, a1, a2, a3;
    if (doStep) {
      a0 = be0i; a1 = be0f; a2 = be0g; a3 = be0o;
#pragma unroll
      for (int j = 0; j < 8; ++j) {
        a0 = __builtin_amdgcn_fdot2(h20[j], W0h[0][j], a0, false);
        a1 = __builtin_amdgcn_fdot2(h20[j], W0h[1][j], a1, false);
        a2 = __builtin_amdgcn_fdot2(h20[j], W0h[2][j], a2, false);
        a3 = __builtin_amdgcn_fdot2(h20[j], W0h[3][j], a3, false);
      }
    }

    if (doHead) {
      __builtin_amdgcn_wave_barrier();
      const int sm = s - 1;
      const float2 ta0 = *(const float2*)&t2b[sg][0];
      const float2 ta1 = *(const float2*)&t2b[sg][2];
      const float2 ta2 = *(const float2*)&t2b[sg][4];
      const float2 ta3 = *(const float2*)&t2b[sg][6];
      const float2 wl0 = *(const float2*)&s_ef2[u][0];
      const float2 wl1 = *(const float2*)&s_ef2[u][2];
      const float2 wl2 = *(const float2*)&s_ef2[u][4];
      const float2 wl3 = *(const float2*)&s_ef2[u][6];
      const float2 wu0 = *(const float2*)&s_ef2[16 + u][0];
      const float2 wu1 = *(const float2*)&s_ef2[16 + u][2];
      const float2 wu2 = *(const float2*)&s_ef2[16 + u][4];
      const float2 wu3 = *(const float2*)&s_ef2[16 + u][6];
      const float fl = f2bl
          + ta0.x * wl0.x + ta0.y * wl0.y + ta1.x * wl1.x + ta1.y * wl1.y
          + ta2.x * wl2.x + ta2.y * wl2.y + ta3.x * wl3.x + ta3.y * wl3.y;
      const float fu = f2bu
          + ta0.x * wu0.x + ta0.y * wu0.y + ta1.x * wu1.x + ta1.y * wu1.y
          + ta2.x * wu2.x + ta2.y * wu2.y + ta3.x * wu3.x + ta3.y * wu3.y;
      fea[((size_t)jN + sm) * 16 + u] = fl;
      fea[((size_t)sm * NMAX + jrow) * 16 + u] = fu;
      if (u < 2) {
        const float4 t1a = *(const float4*)&t1b[sg][0];
        const float4 t1c = *(const float4*)&t1b[sg][4];
        const float4 we0 = *(const float4*)&s_ee2[u * 8];
        const float4 we1 = *(const float4*)&s_ee2[u * 8 + 4];
        float e = e2bias
            + t1a.x * we0.x + t1a.y * we0.y + t1a.z * we0.z + t1a.w * we0.w
            + t1c.x * we1.x + t1c.y * we1.y + t1c.z * we1.z + t1c.w * we1.w;
        const size_t idx = (u == 0) ? ((size_t)jN + sm)
                                    : ((size_t)sm * NMAX + jrow);
        exi[idx] = sgm(e);
      }
    }

    if (doStep) {
      {
        const float iv = sgm(a0), fv = sgm(a1), gv = tanhf_(a2), ov = sgm(a3);
        c0 = fv * c0 + iv * gv;
        rotpack(ov * tanhf_(c0), h20);
      }
      float b0 = be1i, b1 = be1f, b2 = be1g, b3 = be1o;
#pragma unroll
      for (int j = 0; j < 8; ++j) {
        b0 = __builtin_amdgcn_fdot2(h20[j], WAh[0][j], b0, false);
        b1 = __builtin_amdgcn_fdot2(h20[j], WAh[1][j], b1, false);
        b2 = __builtin_amdgcn_fdot2(h20[j], WAh[2][j], b2, false);
        b3 = __builtin_amdgcn_fdot2(h20[j], WAh[3][j], b3, false);
      }
#pragma unroll
      for (int j = 0; j < 8; ++j) {
        b0 = __builtin_amdgcn_fdot2(h21[j], WBh[0][j], b0, false);
        b1 = __builtin_amdgcn_fdot2(h21[j], WBh[1][j], b1, false);
        b2 = __builtin_amdgcn_fdot2(h21[j], WBh[2][j], b2, false);
        b3 = __builtin_amdgcn_fdot2(h21[j], WBh[3][j], b3, false);
      }
      {
        const float iv = sgm(b0), fv = sgm(b1), gv = tanhf_(b2), ov = sgm(b3);
        c1 = fv * c1 + iv * gv;
        rotpack(ov * tanhf_(c1), h21);
      }
      {
        float th = hbias;
#pragma unroll
        for (int j = 0; j < 8; ++j)
          th = __builtin_amdgcn_fdot2(h21[j], WHh[j], th, false);
        th = fmaxf(th, 0.0f);
        if (u < 8) t1b[sg][u] = th; else t2b[sg][u - 8] = th;
      }
      __builtin_amdgcn_wave_barrier();
    }
  }
}

extern "C" void kernel_launch(void* const* d_in, const int* in_sizes, int n_in,
                              void* d_out, int out_size, void* d_ws, size_t ws_size,
                              hipStream_t stream) {
  (void)in_sizes; (void)n_in; (void)out_size; (void)ws_size;
  const float* gene = (const float*)d_in[0];
  const float* entw = (const float*)d_in[1];
  const float* entb = (const float*)d_in[2];
  const float* nwih = (const float*)d_in[4];
  const float* nwhh = (const float*)d_in[5];
  const float* nbih = (const float*)d_in[6];
  const float* nbhh = (const float*)d_in[7];
  const float* exw  = (const float*)d_in[8];
  const float* exb  = (const float*)d_in[9];
  const float* enw  = (const float*)d_in[10];
  const float* enb  = (const float*)d_in[11];
  const float* ewih = (const float*)d_in[13];
  const float* ewhh = (const float*)d_in[14];
  const float* ebih = (const float*)d_in[15];
  const float* ebhh = (const float*)d_in[16];
  const float* ee1w = (const float*)d_in[17];
  const float* ee1b = (const float*)d_in[18];
  const float* ee2w = (const float*)d_in[19];
  const float* ee2b = (const float*)d_in[20];
  const float* ef1w = (const float*)d_in[21];
  const float* ef1b = (const float*)d_in[22];
  const float* ef2w = (const float*)d_in[23];
  const float* ef2b = (const float*)d_in[24];

  // ws layout (bytes):
  //   nflat @ 0         : 10240*128*2 = 2,621,440
  //   X3    @ 2621440   : 4*160*512*16*2 = 10,485,760  (ends 13,107,200)
  //   flags @ 13107200  : 4 ints (memset 4096)
  char* ws = (char*)d_ws;
  unsigned short* nflat = (unsigned short*)(ws);
  unsigned short* X3    = (unsigned short*)(ws + 2621440);
  int* flagP            = (int*)(ws + 13107200);

  hipMemsetAsync(ws + 13107200, 0, 4096, stream);
  node_fused<<<12, 512, 0, stream>>>(gene, entw, entb, nwih, nwhh, nbih, nbhh,
                                     X3, nflat, flagP);
  edge_kernel<<<640, 256, 0, stream>>>(nflat, exw, exb, enw, enb, ewih, ewhh,
                                       ebih, ebhh, ee1w, ee1b, ee2w, ee2b,
                                       ef1w, ef1b, ef2w, ef2b, (float*)d_out);
}